// Round 3
// baseline (718.549 us; speedup 1.0000x reference)
//
#include <hip/hip_runtime.h>
#include <hip/hip_bf16.h>

// PatchedAttention on MI355X (gfx950).
// B=4, T=8192, D=1024, H=16, Dh=64, PATCH=128 -> M=32768 tokens, 256 patches.
// Pipeline: cvt x->bf16 ; transpose W's (B^T layout) ; fused QKV GEMM (bf16 MFMA,
// m97 128^2-tile structure) ; per-(patch,head) attention ; O-proj GEMM -> fp32 out.
// Workspace layout (bytes):
//   xb   @ 0         : 67,108,864  (x bf16 [32768][1024]; reused as attn-out)
//   wqkv @ 67108864  :  6,291,456  (Wq|Wk|Wv transposed bf16 [3072][1024])
//   wot  @ 73400320  :  2,097,152  (Wo transposed bf16 [1024][1024])
//   bqkv @ 75497472  :     12,288  (fused bias f32 [3072])
//   qkv  @ 75509760  : 201,326,592 (QKV bf16 [32768][3072])
//   total: 276,836,352 B (~264 MiB)

#define DEV static __device__ __forceinline__

typedef __attribute__((ext_vector_type(8))) short short8;   // 8 x bf16 (4 VGPR)
typedef __attribute__((ext_vector_type(4))) float f32x4;    // MFMA C/D frag

DEV unsigned short f2b(float f) {  // fp32 -> bf16 RNE
  unsigned u = __builtin_bit_cast(unsigned, f);
  u += 0x7fffu + ((u >> 16) & 1u);
  return (unsigned short)(u >> 16);
}

DEV void load_lds16(const void* g, void* l) {  // async global->LDS, 16B/lane
  __builtin_amdgcn_global_load_lds(
      (const __attribute__((address_space(1))) void*)g,
      (__attribute__((address_space(3))) void*)l, 16, 0, 0);
}

#define MFMA_BF16(a, b, c) __builtin_amdgcn_mfma_f32_16x16x32_bf16((a), (b), (c), 0, 0, 0)

// ---------------- pre-pass kernels ----------------

__global__ void cvt_x_k(const float* __restrict__ x, unsigned short* __restrict__ xb, int n4) {
  int i = blockIdx.x * blockDim.x + threadIdx.x;
  int stride = gridDim.x * blockDim.x;
  for (; i < n4; i += stride) {
    float4 v = ((const float4*)x)[i];
    ushort4 o;
    o.x = f2b(v.x); o.y = f2b(v.y); o.z = f2b(v.z); o.w = f2b(v.w);
    ((ushort4*)xb)[i] = o;
  }
}

// 4x W [1024][1024] (k-major) fp32 -> Wt [1024][1024] (n-major, k contiguous) bf16.
// blockIdx.x in [0,1024): bits [9:8] select weight, low 8 bits select 64x64 tile.
__global__ void twk4(const float* __restrict__ W0, const float* __restrict__ W1,
                     const float* __restrict__ W2, const float* __restrict__ W3,
                     unsigned short* __restrict__ Dqkv, unsigned short* __restrict__ Dot) {
  __shared__ unsigned short tile[64][65];
  const int w = blockIdx.x >> 8;
  const int t = blockIdx.x & 255;
  const float* W = (w == 0) ? W0 : (w == 1) ? W1 : (w == 2) ? W2 : W3;
  unsigned short* Wt = (w == 3) ? Dot : Dqkv + (size_t)w * 1024 * 1024;
  int k0 = (t >> 4) << 6;
  int n0 = (t & 15) << 6;
  int tx = threadIdx.x & 63;
  int ty = threadIdx.x >> 6;
#pragma unroll
  for (int i = 0; i < 16; ++i) {
    int r = (i << 2) + ty;
    tile[r][tx] = f2b(W[(size_t)(k0 + r) * 1024 + n0 + tx]);
  }
  __syncthreads();
#pragma unroll
  for (int i = 0; i < 16; ++i) {
    int n = (i << 2) + ty;
    Wt[(size_t)(n0 + n) * 1024 + k0 + tx] = tile[tx][n];
  }
}

__global__ void fuse_bias_k(const float* __restrict__ bq, const float* __restrict__ bk,
                            const float* __restrict__ bv, float* __restrict__ bqkv) {
  int i = blockIdx.x * 256 + threadIdx.x;
  if (i < 1024) bqkv[i] = bq[i];
  else if (i < 2048) bqkv[i] = bk[i - 1024];
  else if (i < 3072) bqkv[i] = bv[i - 2048];
}

// ---------------- GEMM: C[M,N] = A[M,K] * Bt[N,K]^T + bias ----------------
// m97 structure: 128x128 tile, BK=32, 4 waves (2x2), 4x4 16x16x32 frags/wave.

template <bool OUT_F32>
__global__ __launch_bounds__(256)
void gemm_bt(const unsigned short* __restrict__ A,
             const unsigned short* __restrict__ Bt,
             const float* __restrict__ bias,
             void* __restrict__ Cv, int M, int N, int K) {
  __shared__ __align__(16) unsigned short sA[128 * 32];
  __shared__ __align__(16) unsigned short sB[128 * 32];

  int nwg = gridDim.x;
  int bid = blockIdx.x;
  int wg = bid;
  if ((nwg & 7) == 0) {              // bijective XCD swizzle (nwg % 8 == 0)
    int cpx = nwg >> 3;
    wg = (bid & 7) * cpx + (bid >> 3);
  }
  const int nbn = N >> 7;
  const int bm = wg / nbn;
  const int bn = wg - bm * nbn;

  const int tid = threadIdx.x;
  const int lane = tid & 63;
  const int wv = tid >> 6;
  const int wr = wv >> 1, wc = wv & 1;
  const int fr = lane & 15;
  const int fks = (lane >> 4) << 3;

  // staging: thread covers 8 elems at flat idx tid*8 (rows 0-63), +2048 (rows 64-127)
  const int srow = tid >> 2;
  const int scol = (tid & 3) << 3;
  const unsigned short* gA = A + (size_t)(bm * 128 + srow) * K + scol;
  const unsigned short* gB = Bt + (size_t)(bn * 128 + srow) * K + scol;
  unsigned short* lA = sA + (wv << 9);  // wave-uniform LDS dest (+lane*16B by HW)
  unsigned short* lB = sB + (wv << 9);

  const unsigned short* pa = sA + (wr * 64 + fr) * 32 + fks;
  const unsigned short* pb = sB + (wc * 64 + fr) * 32 + fks;

  f32x4 acc[4][4] = {};

  for (int k0 = 0; k0 < K; k0 += 32) {
    load_lds16(gA + k0, lA);
    load_lds16(gA + (size_t)64 * K + k0, lA + 2048);
    load_lds16(gB + k0, lB);
    load_lds16(gB + (size_t)64 * K + k0, lB + 2048);
    __syncthreads();  // compiler drains vmcnt before s_barrier
    short8 af[4], bfv[4];
#pragma unroll
    for (int i = 0; i < 4; ++i) af[i] = *(const short8*)(pa + i * 512);
#pragma unroll
    for (int i = 0; i < 4; ++i) bfv[i] = *(const short8*)(pb + i * 512);
#pragma unroll
    for (int i = 0; i < 4; ++i)
#pragma unroll
      for (int j = 0; j < 4; ++j)
        acc[i][j] = MFMA_BF16(af[i], bfv[j], acc[i][j]);
    __syncthreads();
  }

  // epilogue: C/D layout col = lane&15, row = (lane>>4)*4 + reg  [m89-verified]
  const int grow0 = bm * 128 + wr * 64 + ((lane >> 4) << 2);
  const int gcol0 = bn * 128 + wc * 64 + fr;
#pragma unroll
  for (int j = 0; j < 4; ++j) {
    const int gc = gcol0 + j * 16;
    const float bv_ = bias[gc];
#pragma unroll
    for (int i = 0; i < 4; ++i) {
      const int gr = grow0 + i * 16;
#pragma unroll
      for (int r = 0; r < 4; ++r) {
        float v = acc[i][j][r] + bv_;
        if (OUT_F32) ((float*)Cv)[(size_t)(gr + r) * N + gc] = v;
        else ((unsigned short*)Cv)[(size_t)(gr + r) * N + gc] = f2b(v);
      }
    }
  }
}

// ---------------- attention: one block per (patch, head) ----------------
// 4 waves; wave w owns q-rows [w*32, w*32+32). S = q k^T (K=64), softmax, O = P v.

__global__ __launch_bounds__(256)
void attn_k(const unsigned short* __restrict__ qkv, unsigned short* __restrict__ out) {
  const int bh = blockIdx.x;
  const int p = bh >> 4, h = bh & 15;
  const int tid = threadIdx.x, lane = tid & 63, wv = tid >> 6;
  const int fr = lane & 15, fks = (lane >> 4) << 3;

  __shared__ __align__(16) unsigned short vt[64][136];        // V^T [dim][token], +pad
  __shared__ __align__(16) unsigned short pls[4][32][136];    // per-wave P staging

  const size_t rowbase = (size_t)p * 128 * 3072;

  // stage V transposed: V[t][d] -> vt[d][t]
  {
    const unsigned short* vsrc = qkv + rowbase + 2048 + (size_t)h * 64;
#pragma unroll
    for (int it = 0; it < 8; ++it) {
      int idx = tid + it * 256;
      int t = idx >> 4;
      int d4 = (idx & 15) << 2;
      ushort4 vv = *(const ushort4*)(vsrc + (size_t)t * 3072 + d4);
      vt[d4 + 0][t] = vv.x; vt[d4 + 1][t] = vv.y;
      vt[d4 + 2][t] = vv.z; vt[d4 + 3][t] = vv.w;
    }
  }

  // Q fragments (A operand: row = lane&15, k = (lane>>4)*8.. contiguous)
  short8 qf[2][2];
  {
    const unsigned short* qsrc = qkv + rowbase + (size_t)(wv * 32) * 3072 + h * 64;
#pragma unroll
    for (int mf = 0; mf < 2; ++mf)
#pragma unroll
      for (int kc = 0; kc < 2; ++kc)
        qf[mf][kc] = *(const short8*)(qsrc + (size_t)(mf * 16 + fr) * 3072 + kc * 32 + fks);
  }

  // S = q k^T : [32 x 128], K=64 (2 k-chunks). K rows are B operand (n=token).
  f32x4 s[2][8] = {};
  {
    const unsigned short* ksrc = qkv + rowbase + 1024 + (size_t)h * 64;
#pragma unroll
    for (int kc = 0; kc < 2; ++kc)
#pragma unroll
      for (int nf = 0; nf < 8; ++nf) {
        short8 kf = *(const short8*)(ksrc + (size_t)(nf * 16 + fr) * 3072 + kc * 32 + fks);
        s[0][nf] = MFMA_BF16(qf[0][kc], kf, s[0][nf]);
        s[1][nf] = MFMA_BF16(qf[1][kc], kf, s[1][nf]);
      }
  }
  __syncthreads();  // vt staged (V-load latency hidden under QK^T)

  // wave-parallel softmax. C layout: lane holds rows (lane>>4)*4+r, col lane&15.
  // scores scaled by 1/sqrt(64)=0.125 inside exp2.
  const float c0 = 0.125f * 1.44269504088896f;
  float sm[2][4];
#pragma unroll
  for (int mf = 0; mf < 2; ++mf)
#pragma unroll
    for (int r = 0; r < 4; ++r) {
      float m = s[mf][0][r];
#pragma unroll
      for (int nf = 1; nf < 8; ++nf) m = fmaxf(m, s[mf][nf][r]);
      m = fmaxf(m, __shfl_xor(m, 1));
      m = fmaxf(m, __shfl_xor(m, 2));
      m = fmaxf(m, __shfl_xor(m, 4));
      m = fmaxf(m, __shfl_xor(m, 8));
      float su = 0.f;
#pragma unroll
      for (int nf = 0; nf < 8; ++nf) {
        float e = exp2f((s[mf][nf][r] - m) * c0);
        s[mf][nf][r] = e;
        su += e;
      }
      su += __shfl_xor(su, 1);
      su += __shfl_xor(su, 2);
      su += __shfl_xor(su, 4);
      su += __shfl_xor(su, 8);
      sm[mf][r] = su;
    }

  // P (C layout) -> per-wave LDS -> A-fragment layout
#pragma unroll
  for (int mf = 0; mf < 2; ++mf)
#pragma unroll
    for (int nf = 0; nf < 8; ++nf)
#pragma unroll
      for (int r = 0; r < 4; ++r)
        pls[wv][mf * 16 + ((lane >> 4) << 2) + r][nf * 16 + fr] = f2b(s[mf][nf][r]);

  // O = P v : [32 x 64], K=128 (4 k-chunks). B operand from vt (n=dim, k=token).
  f32x4 o[2][4] = {};
#pragma unroll
  for (int kc = 0; kc < 4; ++kc) {
    short8 pf0 = *(const short8*)&pls[wv][fr][kc * 32 + fks];
    short8 pf1 = *(const short8*)&pls[wv][16 + fr][kc * 32 + fks];
#pragma unroll
    for (int nf = 0; nf < 4; ++nf) {
      short8 vf = *(const short8*)&vt[nf * 16 + fr][kc * 32 + fks];
      o[0][nf] = MFMA_BF16(pf0, vf, o[0][nf]);
      o[1][nf] = MFMA_BF16(pf1, vf, o[1][nf]);
    }
  }

  // divide by rowsum, store bf16
  unsigned short* obase = out + (size_t)(p * 128 + wv * 32) * 1024 + h * 64;
#pragma unroll
  for (int mf = 0; mf < 2; ++mf)
#pragma unroll
    for (int nf = 0; nf < 4; ++nf)
#pragma unroll
      for (int r = 0; r < 4; ++r) {
        int row = mf * 16 + ((lane >> 4) << 2) + r;
        float val = o[mf][nf][r] / sm[mf][r];
        obase[(size_t)row * 1024 + nf * 16 + fr] = f2b(val);
      }
}

// ---------------- launcher ----------------

extern "C" void kernel_launch(void* const* d_in, const int* in_sizes, int n_in,
                              void* d_out, int out_size, void* d_ws, size_t ws_size,
                              hipStream_t stream) {
  const float* x  = (const float*)d_in[0];
  // d_in[1] = coords, unused by reference
  const float* Wq = (const float*)d_in[2];
  const float* bq = (const float*)d_in[3];
  const float* Wk = (const float*)d_in[4];
  const float* bk = (const float*)d_in[5];
  const float* Wv = (const float*)d_in[6];
  const float* bv = (const float*)d_in[7];
  const float* Wo = (const float*)d_in[8];
  const float* bo = (const float*)d_in[9];

  char* ws = (char*)d_ws;
  unsigned short* xb   = (unsigned short*)(ws);
  unsigned short* wqkv = (unsigned short*)(ws + 67108864);
  unsigned short* wot  = (unsigned short*)(ws + 73400320);
  float*          bqkv = (float*)(ws + 75497472);
  unsigned short* qkv  = (unsigned short*)(ws + 75509760);

  cvt_x_k<<<2048, 256, 0, stream>>>(x, xb, (32768 * 1024) / 4);
  twk4<<<1024, 256, 0, stream>>>(Wq, Wk, Wv, Wo, wqkv, wot);
  fuse_bias_k<<<12, 256, 0, stream>>>(bq, bk, bv, bqkv);

  // QKV: [32768,1024] x [3072,1024]^T -> bf16 [32768,3072]
  gemm_bt<false><<<6144, 256, 0, stream>>>(xb, wqkv, bqkv, qkv, 32768, 3072, 1024);
  // attention: 256 patches x 16 heads; writes bf16 [32768,1024] into xb
  attn_k<<<4096, 256, 0, stream>>>(qkv, xb);
  // O-proj: [32768,1024] x [1024,1024]^T + bo -> fp32 d_out
  gemm_bt<true><<<2048, 256, 0, stream>>>(xb, wot, bo, d_out, 32768, 1024, 1024);
}